// Round 9
// baseline (861.325 us; speedup 1.0000x reference)
//
#include <hip/hip_runtime.h>
#include <hip/hip_bf16.h>

// GCN restructured + fused, bf16 intermediates:
//   xb = bf16(x)
//   h1 = relu((Ahat xb) @ W1 + b1)  -- fused gather(bf16)+GEMM (dst-CSR)
//   h2 = relu((Ahat h1) @ W2 + b2)  -- fused gather(bf16)+GEMM, stored [8][N][16]
//   Spart = src-major streaming scatter-pool of (Ahat h2) into LDS per-graph acc
//   out = ((S@W3)/cnt + b3) @ Wlin + blin
// Two CSRs (dst-major for layers, src-major with (g,w) for pool) built per call
// via one packed-u64 scan.

#define NN 100000
#define NE 800000
#define NG 512
#define CCH 64                       // src chunks in pool_scatter
#define CHSZ ((NN + CCH - 1) / CCH)  // 1563

typedef unsigned int u32;
typedef unsigned long long u64;

// RNE pack of two fp32 -> packed bf16x2 (lo in low half)
__device__ __forceinline__ u32 pack_bf2(float lo, float hi) {
    u32 ul = __float_as_uint(lo);
    u32 uh = __float_as_uint(hi);
    ul = (ul + 0x7fffu + ((ul >> 16) & 1u)) >> 16;
    uh = (uh + 0x7fffu + ((uh >> 16) & 1u)) & 0xffff0000u;
    return uh | ul;
}

#define BF_FMA8(ACC, V, W_) do { \
    (ACC)[0] += __uint_as_float((V).x << 16) * (W_); \
    (ACC)[1] += __uint_as_float((V).x & 0xffff0000u) * (W_); \
    (ACC)[2] += __uint_as_float((V).y << 16) * (W_); \
    (ACC)[3] += __uint_as_float((V).y & 0xffff0000u) * (W_); \
    (ACC)[4] += __uint_as_float((V).z << 16) * (W_); \
    (ACC)[5] += __uint_as_float((V).z & 0xffff0000u) * (W_); \
    (ACC)[6] += __uint_as_float((V).w << 16) * (W_); \
    (ACC)[7] += __uint_as_float((V).w & 0xffff0000u) * (W_); \
} while (0)

#define BF_FMA4(ACC, V, W_) do { \
    (ACC)[0] += __uint_as_float((V).x << 16) * (W_); \
    (ACC)[1] += __uint_as_float((V).x & 0xffff0000u) * (W_); \
    (ACC)[2] += __uint_as_float((V).y << 16) * (W_); \
    (ACC)[3] += __uint_as_float((V).y & 0xffff0000u) * (W_); \
} while (0)

#define FMA4(A, H, W_) do { (A).x += (H).x * (W_); (A).y += (H).y * (W_); \
                            (A).z += (H).z * (W_); (A).w += (H).w * (W_); } while (0)

// ---------------- x -> bf16 ----------------
__global__ __launch_bounds__(256) void xcast(const float* __restrict__ x,
                                             u32* __restrict__ xb, int n4) {
    int i = blockIdx.x * 256 + threadIdx.x;
    if (i >= n4) return;
    const float4 v = *reinterpret_cast<const float4*>(&x[i * 4]);
    *reinterpret_cast<uint2*>(&xb[i * 2]) =
        make_uint2(pack_bf2(v.x, v.y), pack_bf2(v.z, v.w));
}

// ---------------- degrees (both directions) ----------------
__global__ __launch_bounds__(256) void deg_count2(const int* __restrict__ ei,
                                                  int* __restrict__ deg_dst,
                                                  int* __restrict__ deg_src, int nE) {
    int e = blockIdx.x * 256 + threadIdx.x;
    if (e >= nE) return;
    atomicAdd(&deg_dst[ei[nE + e]], 1);
    atomicAdd(&deg_src[ei[e]], 1);
}

// ---------------- packed dual exclusive scan (lo=dst, hi=src) ----------------
__global__ __launch_bounds__(256) void scanA2(const int* __restrict__ dd,
                                              const int* __restrict__ ds,
                                              int* __restrict__ exd,
                                              int* __restrict__ exs,
                                              u64* __restrict__ bsum, int n) {
    __shared__ u64 sdata[256];
    const int t = threadIdx.x;
    const int idx = blockIdx.x * 1024 + t * 4;
    u64 v[4];
#pragma unroll
    for (int k = 0; k < 4; ++k)
        v[k] = (idx + k < n) ? ((u64)(u32)dd[idx + k] | ((u64)(u32)ds[idx + k] << 32)) : 0ull;
    u64 ts = v[0] + v[1] + v[2] + v[3];
    sdata[t] = ts;
    __syncthreads();
    for (int off = 1; off < 256; off <<= 1) {
        u64 val = (t >= off) ? sdata[t - off] : 0ull;
        __syncthreads();
        sdata[t] += val;
        __syncthreads();
    }
    u64 run = sdata[t] - ts;
    if (t == 255) bsum[blockIdx.x] = sdata[255];
#pragma unroll
    for (int k = 0; k < 4; ++k) {
        if (idx + k < n) {
            exd[idx + k] = (int)(run & 0xffffffffull);
            exs[idx + k] = (int)(run >> 32);
        }
        run += v[k];
    }
}

__global__ __launch_bounds__(128) void scanB2(u64* __restrict__ bsum, int nb) {
    __shared__ u64 s[128];
    const int t = threadIdx.x;
    u64 orig = (t < nb) ? bsum[t] : 0ull;
    s[t] = orig;
    __syncthreads();
    for (int off = 1; off < 128; off <<= 1) {
        u64 val = (t >= off) ? s[t - off] : 0ull;
        __syncthreads();
        s[t] += val;
        __syncthreads();
    }
    if (t < nb) bsum[t] = s[t] - orig;
}

__global__ __launch_bounds__(256) void scanC2(int* __restrict__ rpd,
                                              int* __restrict__ rps,
                                              const u64* __restrict__ bsum,
                                              int* __restrict__ curd,
                                              int* __restrict__ curs,
                                              const int* __restrict__ degd,
                                              float* __restrict__ dinv,
                                              int n, int total) {
    int i = blockIdx.x * 256 + threadIdx.x;
    if (i < n) {
        const u64 b = bsum[i >> 10];
        int vd = rpd[i] + (int)(b & 0xffffffffull);
        int vs = rps[i] + (int)(b >> 32);
        rpd[i] = vd; curd[i] = vd;
        rps[i] = vs; curs[i] = vs;
        dinv[i] = rsqrtf((float)degd[i] + 1.0f);
    }
    if (i == n) { rpd[n] = total; rps[n] = total; }
}

// ---------------- dual CSR fill ----------------
// dst-CSR: cw[pos] = (src, w fp32)   src-CSR: se[pos] = g<<16 | bf16(w)
__global__ __launch_bounds__(256) void fill2(const int* __restrict__ ei,
                                             const float* __restrict__ dinv,
                                             const int* __restrict__ batch,
                                             int* __restrict__ curd,
                                             int* __restrict__ curs,
                                             int2* __restrict__ cw,
                                             u32* __restrict__ se, int nE) {
    int e = blockIdx.x * 256 + threadIdx.x;
    if (e >= nE) return;
    const int s = ei[e];
    const int d = ei[nE + e];
    const float wv = dinv[s] * dinv[d];
    const int p1 = atomicAdd(&curd[d], 1);
    cw[p1] = make_int2(s, __float_as_int(wv));
    u32 uw = __float_as_uint(wv);
    uw = (uw + 0x7fffu + ((uw >> 16) & 1u)) >> 16;
    const int p2 = atomicAdd(&curs[s], 1);
    se[p2] = ((u32)batch[d] << 16) | uw;
}

// ---------------- layer 1: h1 = relu((Ahat xb)@W1 + b1), bf16 in/out --------
__global__ __launch_bounds__(256) void gather_gemm_l1(const u32* __restrict__ X,
                                                      const int* __restrict__ rp,
                                                      const int2* __restrict__ cw,
                                                      const float* __restrict__ dinv,
                                                      const float* __restrict__ W,
                                                      const float* __restrict__ bias,
                                                      u32* __restrict__ out, int n) {
    constexpr int AS = 36;
    __shared__ float agg[32 * AS];
    __shared__ float Wl[32 * 64];
    float4 wr[2];
#pragma unroll
    for (int i = 0; i < 2; ++i)
        wr[i] = *reinterpret_cast<const float4*>(&W[(threadIdx.x + i * 256) * 4]);

    const int nl = threadIdx.x >> 3;
    const int j = threadIdx.x & 7;
    const int node = blockIdx.x * 32 + nl;
    float a0[4], a1[4], a2[4], a3[4];
#pragma unroll
    for (int q = 0; q < 4; ++q) { a0[q] = 0.f; a1[q] = 0.f; a2[q] = 0.f; a3[q] = 0.f; }
    if (node < n) {
        const float di = dinv[node];
        const float c = di * di;
        const uint2 sv = *reinterpret_cast<const uint2*>(&X[(long long)node * 16 + j * 2]);
        BF_FMA4(a0, sv, c);
        int e = rp[node];
        const int end = rp[node + 1];
        for (; e + 4 <= end; e += 4) {
            const int2 c0 = cw[e], c1 = cw[e + 1], c2 = cw[e + 2], c3 = cw[e + 3];
            const uint2 h0 = *reinterpret_cast<const uint2*>(&X[(long long)c0.x * 16 + j * 2]);
            const uint2 h1 = *reinterpret_cast<const uint2*>(&X[(long long)c1.x * 16 + j * 2]);
            const uint2 h2 = *reinterpret_cast<const uint2*>(&X[(long long)c2.x * 16 + j * 2]);
            const uint2 h3 = *reinterpret_cast<const uint2*>(&X[(long long)c3.x * 16 + j * 2]);
            BF_FMA4(a0, h0, __int_as_float(c0.y));
            BF_FMA4(a1, h1, __int_as_float(c1.y));
            BF_FMA4(a2, h2, __int_as_float(c2.y));
            BF_FMA4(a3, h3, __int_as_float(c3.y));
        }
        if (e + 2 <= end) {
            const int2 c0 = cw[e], c1 = cw[e + 1];
            const uint2 h0 = *reinterpret_cast<const uint2*>(&X[(long long)c0.x * 16 + j * 2]);
            const uint2 h1 = *reinterpret_cast<const uint2*>(&X[(long long)c1.x * 16 + j * 2]);
            BF_FMA4(a0, h0, __int_as_float(c0.y));
            BF_FMA4(a1, h1, __int_as_float(c1.y));
            e += 2;
        }
        if (e < end) {
            const int2 c0 = cw[e];
            const uint2 h0 = *reinterpret_cast<const uint2*>(&X[(long long)c0.x * 16 + j * 2]);
            BF_FMA4(a0, h0, __int_as_float(c0.y));
        }
#pragma unroll
        for (int q = 0; q < 4; ++q) a0[q] += a1[q] + a2[q] + a3[q];
    }
    *reinterpret_cast<float4*>(&agg[nl * AS + j * 4]) =
        make_float4(a0[0], a0[1], a0[2], a0[3]);
#pragma unroll
    for (int i = 0; i < 2; ++i)
        *reinterpret_cast<float4*>(&Wl[(threadIdx.x + i * 256) * 4]) = wr[i];
    __syncthreads();

    const int r0 = (threadIdx.x >> 4) * 2;
    const int cg = (threadIdx.x & 15) * 4;
    float4 o0 = make_float4(0.f, 0.f, 0.f, 0.f);
    float4 o1 = o0;
#pragma unroll 8
    for (int k = 0; k < 32; ++k) {
        const float4 wv = *reinterpret_cast<const float4*>(&Wl[k * 64 + cg]);
        const float x0 = agg[r0 * AS + k];
        const float x1 = agg[(r0 + 1) * AS + k];
        FMA4(o0, wv, x0);
        FMA4(o1, wv, x1);
    }
    const float4 bv = *reinterpret_cast<const float4*>(&bias[cg]);
    o0.x = fmaxf(o0.x + bv.x, 0.f); o0.y = fmaxf(o0.y + bv.y, 0.f);
    o0.z = fmaxf(o0.z + bv.z, 0.f); o0.w = fmaxf(o0.w + bv.w, 0.f);
    o1.x = fmaxf(o1.x + bv.x, 0.f); o1.y = fmaxf(o1.y + bv.y, 0.f);
    o1.z = fmaxf(o1.z + bv.z, 0.f); o1.w = fmaxf(o1.w + bv.w, 0.f);
    const int row0 = blockIdx.x * 32 + r0;
    if (row0 < n)
        *reinterpret_cast<uint2*>(&out[(long long)row0 * 32 + (cg >> 1)]) =
            make_uint2(pack_bf2(o0.x, o0.y), pack_bf2(o0.z, o0.w));
    if (row0 + 1 < n)
        *reinterpret_cast<uint2*>(&out[(long long)(row0 + 1) * 32 + (cg >> 1)]) =
            make_uint2(pack_bf2(o1.x, o1.y), pack_bf2(o1.z, o1.w));
}

// ---------------- layer 2: h2 = relu((Ahat h1)@W2 + b2) --------------------
// Output layout: [8 slices][N][16 feats] bf16 (slice-contiguous for pool).
__global__ __launch_bounds__(256) void gather_gemm_l2(const u32* __restrict__ X,
                                                      const int* __restrict__ rp,
                                                      const int2* __restrict__ cw,
                                                      const float* __restrict__ dinv,
                                                      const float* __restrict__ W,
                                                      const float* __restrict__ bias,
                                                      u32* __restrict__ out, int n) {
    constexpr int AS = 68;
    __shared__ float agg[32 * AS];
    __shared__ float Wl[64 * 128];
    float4 wr[8];
#pragma unroll
    for (int i = 0; i < 8; ++i)
        wr[i] = *reinterpret_cast<const float4*>(&W[(threadIdx.x + i * 256) * 4]);

    const int nl = threadIdx.x >> 3;
    const int j = threadIdx.x & 7;
    const int node = blockIdx.x * 32 + nl;
    float a0[8], a1[8], a2[8], a3[8];
#pragma unroll
    for (int q = 0; q < 8; ++q) { a0[q] = 0.f; a1[q] = 0.f; a2[q] = 0.f; a3[q] = 0.f; }
    if (node < n) {
        const float di = dinv[node];
        const float c = di * di;
        const uint4 sv = *reinterpret_cast<const uint4*>(&X[(long long)node * 32 + j * 4]);
        BF_FMA8(a0, sv, c);
        int e = rp[node];
        const int end = rp[node + 1];
        for (; e + 4 <= end; e += 4) {
            const int2 c0 = cw[e], c1 = cw[e + 1], c2 = cw[e + 2], c3 = cw[e + 3];
            const uint4 h0 = *reinterpret_cast<const uint4*>(&X[(long long)c0.x * 32 + j * 4]);
            const uint4 h1 = *reinterpret_cast<const uint4*>(&X[(long long)c1.x * 32 + j * 4]);
            const uint4 h2 = *reinterpret_cast<const uint4*>(&X[(long long)c2.x * 32 + j * 4]);
            const uint4 h3 = *reinterpret_cast<const uint4*>(&X[(long long)c3.x * 32 + j * 4]);
            BF_FMA8(a0, h0, __int_as_float(c0.y));
            BF_FMA8(a1, h1, __int_as_float(c1.y));
            BF_FMA8(a2, h2, __int_as_float(c2.y));
            BF_FMA8(a3, h3, __int_as_float(c3.y));
        }
        if (e + 2 <= end) {
            const int2 c0 = cw[e], c1 = cw[e + 1];
            const uint4 h0 = *reinterpret_cast<const uint4*>(&X[(long long)c0.x * 32 + j * 4]);
            const uint4 h1 = *reinterpret_cast<const uint4*>(&X[(long long)c1.x * 32 + j * 4]);
            BF_FMA8(a0, h0, __int_as_float(c0.y));
            BF_FMA8(a1, h1, __int_as_float(c1.y));
            e += 2;
        }
        if (e < end) {
            const int2 c0 = cw[e];
            const uint4 h0 = *reinterpret_cast<const uint4*>(&X[(long long)c0.x * 32 + j * 4]);
            BF_FMA8(a0, h0, __int_as_float(c0.y));
        }
#pragma unroll
        for (int q = 0; q < 8; ++q) a0[q] += a1[q] + a2[q] + a3[q];
    }
    *reinterpret_cast<float4*>(&agg[nl * AS + j * 8]) =
        make_float4(a0[0], a0[1], a0[2], a0[3]);
    *reinterpret_cast<float4*>(&agg[nl * AS + j * 8 + 4]) =
        make_float4(a0[4], a0[5], a0[6], a0[7]);
#pragma unroll
    for (int i = 0; i < 8; ++i)
        *reinterpret_cast<float4*>(&Wl[(threadIdx.x + i * 256) * 4]) = wr[i];
    __syncthreads();

    const int r0 = (threadIdx.x >> 5) * 4;
    const int cg = (threadIdx.x & 31) * 4;
    float4 o0 = make_float4(0.f, 0.f, 0.f, 0.f);
    float4 o1 = o0, o2 = o0, o3 = o0;
#pragma unroll 8
    for (int k = 0; k < 64; ++k) {
        const float4 wv = *reinterpret_cast<const float4*>(&Wl[k * 128 + cg]);
        const float x0 = agg[(r0 + 0) * AS + k];
        const float x1 = agg[(r0 + 1) * AS + k];
        const float x2 = agg[(r0 + 2) * AS + k];
        const float x3 = agg[(r0 + 3) * AS + k];
        FMA4(o0, wv, x0);
        FMA4(o1, wv, x1);
        FMA4(o2, wv, x2);
        FMA4(o3, wv, x3);
    }
    const float4 bv = *reinterpret_cast<const float4*>(&bias[cg]);
    const int row0 = blockIdx.x * 32 + r0;
    const int slice = cg >> 4;
    const int within = (cg & 15) >> 1;   // u32 offset within 8-u32 slice row
    float4 oo[4] = {o0, o1, o2, o3};
#pragma unroll
    for (int r = 0; r < 4; ++r) {
        float4 o = oo[r];
        o.x = fmaxf(o.x + bv.x, 0.f); o.y = fmaxf(o.y + bv.y, 0.f);
        o.z = fmaxf(o.z + bv.z, 0.f); o.w = fmaxf(o.w + bv.w, 0.f);
        if (row0 + r < n)
            *reinterpret_cast<uint2*>(
                &out[((long long)slice * n + (row0 + r)) * 8 + within]) =
                make_uint2(pack_bf2(o.x, o.y), pack_bf2(o.z, o.w));
    }
}

// ---------------- src-major streaming scatter pool ----------------
// Grid = 8 slices x CCH chunks. Block: LDS S_part[512][17] fp32, stream srcs
// of its chunk (h2 slice rows sequential), ds_add contributions per out-edge.
__global__ __launch_bounds__(256) void pool_scatter(const u32* __restrict__ H,
                                                    const int* __restrict__ rps,
                                                    const u32* __restrict__ se,
                                                    const float* __restrict__ dinv,
                                                    const int* __restrict__ batch,
                                                    float* __restrict__ Spart, int n) {
    __shared__ float sp[512 * 17];
    for (int i = threadIdx.x; i < 512 * 17; i += 256) sp[i] = 0.f;
    __syncthreads();
    const int slice = blockIdx.x & 7;
    const int chunk = blockIdx.x >> 3;
    const u32* Hs = H + (long long)slice * n * 8;
    const int s0 = chunk * CHSZ;
    const int s1 = (s0 + CHSZ < n) ? (s0 + CHSZ) : n;
    for (int src = s0 + threadIdx.x; src < s1; src += 256) {
        const uint4 r0 = *reinterpret_cast<const uint4*>(&Hs[(long long)src * 8]);
        const uint4 r1 = *reinterpret_cast<const uint4*>(&Hs[(long long)src * 8 + 4]);
        float h[16];
        h[0] = __uint_as_float(r0.x << 16);  h[1] = __uint_as_float(r0.x & 0xffff0000u);
        h[2] = __uint_as_float(r0.y << 16);  h[3] = __uint_as_float(r0.y & 0xffff0000u);
        h[4] = __uint_as_float(r0.z << 16);  h[5] = __uint_as_float(r0.z & 0xffff0000u);
        h[6] = __uint_as_float(r0.w << 16);  h[7] = __uint_as_float(r0.w & 0xffff0000u);
        h[8] = __uint_as_float(r1.x << 16);  h[9] = __uint_as_float(r1.x & 0xffff0000u);
        h[10] = __uint_as_float(r1.y << 16); h[11] = __uint_as_float(r1.y & 0xffff0000u);
        h[12] = __uint_as_float(r1.z << 16); h[13] = __uint_as_float(r1.z & 0xffff0000u);
        h[14] = __uint_as_float(r1.w << 16); h[15] = __uint_as_float(r1.w & 0xffff0000u);
        const float di = dinv[src];
        const float c = di * di;
        const int gs = batch[src];
#pragma unroll
        for (int f = 0; f < 16; ++f) atomicAdd(&sp[gs * 17 + f], h[f] * c);
        int e = rps[src];
        const int ee = rps[src + 1];
        for (; e < ee; ++e) {
            const u32 m = se[e];
            const int g = m >> 16;
            const float wv = __uint_as_float(m << 16);
#pragma unroll
            for (int f = 0; f < 16; ++f) atomicAdd(&sp[g * 17 + f], h[f] * wv);
        }
    }
    __syncthreads();
    float* outp = &Spart[(long long)(slice * CCH + chunk) * (512 * 16)];
    for (int i = threadIdx.x; i < 512 * 16; i += 256)
        outp[i] = sp[(i >> 4) * 17 + (i & 15)];
}

// ---------------- final: reduce Spart, GEMM W3, mean, linear ----------------
__device__ __forceinline__ int lower_bound_i(const int* __restrict__ a, int n, int key) {
    int lo = 0, hi = n;
    while (lo < hi) {
        int mid = (lo + hi) >> 1;
        if (a[mid] < key) lo = mid + 1; else hi = mid;
    }
    return lo;
}

__global__ __launch_bounds__(256) void final_k(const float* __restrict__ Spart,
                                               const int* __restrict__ batch,
                                               const float* __restrict__ W3,
                                               const float* __restrict__ b3,
                                               const float* __restrict__ Wlin,
                                               const float* __restrict__ blin,
                                               float* __restrict__ out, int n) {
    __shared__ float srow[128];
    __shared__ float prow[256];
    const int g = blockIdx.x;
    const int t = threadIdx.x;
    if (t < 128) {
        const int slice = t >> 4;
        const int within = t & 15;
        float s = 0.f;
        for (int c = 0; c < CCH; ++c)
            s += Spart[(long long)(slice * CCH + c) * (512 * 16) + g * 16 + within];
        srow[t] = s;
    }
    __syncthreads();
    const int start = lower_bound_i(batch, n, g);
    const int end = lower_bound_i(batch, n, g + 1);
    const float cnt = (float)(end - start);
    const float inv = 1.0f / fmaxf(cnt, 1.0f);
    const float bscale = cnt * inv;
    float p = 0.f;
    for (int k = 0; k < 128; ++k) p += srow[k] * W3[k * 256 + t];
    prow[t] = p * inv + b3[t] * bscale;
    __syncthreads();
    if (t < 10) {
        float a = blin[t];
        for (int f = 0; f < 256; ++f) a += prow[f] * Wlin[f * 10 + t];
        out[g * 10 + t] = a;
    }
}

extern "C" void kernel_launch(void* const* d_in, const int* in_sizes, int n_in,
                              void* d_out, int out_size, void* d_ws, size_t ws_size,
                              hipStream_t stream) {
    const float* x     = (const float*)d_in[0];
    const int*   ei    = (const int*)d_in[1];
    const int*   batch = (const int*)d_in[2];
    const float* W1    = (const float*)d_in[3];
    const float* bc1   = (const float*)d_in[4];
    const float* W2    = (const float*)d_in[5];
    const float* bc2   = (const float*)d_in[6];
    const float* W3    = (const float*)d_in[7];
    const float* bc3   = (const float*)d_in[8];
    const float* Wlin  = (const float*)d_in[9];
    const float* blin  = (const float*)d_in[10];
    float* out = (float*)d_out;

    char* w = (char*)d_ws;
    int*   deg_dst = (int*)w;              w += 131072 * 4;
    int*   deg_src = (int*)w;              w += 131072 * 4;   // contiguous w/ deg_dst
    int*   rpd     = (int*)w;              w += 131072 * 4;
    int*   rps     = (int*)w;              w += 131072 * 4;
    int*   curd    = (int*)w;              w += 131072 * 4;
    int*   curs    = (int*)w;              w += 131072 * 4;
    u64*   bsum    = (u64*)w;              w += 256 * 8;
    float* dinv    = (float*)w;            w += 131072 * 4;
    int2*  cw      = (int2*)w;             w += (long long)NE * 8;
    u32*   se      = (u32*)w;              w += (long long)NE * 4;
    u32*   xb      = (u32*)w;              w += (long long)NN * 16 * 4;
    u32*   Q       = (u32*)w;              w += (long long)NN * 32 * 4;   // h1 bf16
    u32*   P       = (u32*)w;              w += (long long)NN * 64 * 4;   // h2 [8][N][16]
    float* Spart   = (float*)w;            w += (long long)8 * CCH * 512 * 16 * 4;

    const int nbScanA = (NN + 1023) / 1024;  // 98 <= 128

    hipMemsetAsync(deg_dst, 0, 2 * 131072 * sizeof(int), stream);
    xcast<<<(NN * 8 + 255) / 256, 256, 0, stream>>>(x, xb, NN * 8);
    deg_count2<<<(NE + 255) / 256, 256, 0, stream>>>(ei, deg_dst, deg_src, NE);
    scanA2<<<nbScanA, 256, 0, stream>>>(deg_dst, deg_src, rpd, rps, bsum, NN);
    scanB2<<<1, 128, 0, stream>>>(bsum, nbScanA);
    scanC2<<<(NN + 256) / 256, 256, 0, stream>>>(rpd, rps, bsum, curd, curs,
                                                 deg_dst, dinv, NN, NE);
    fill2<<<(NE + 255) / 256, 256, 0, stream>>>(ei, dinv, batch, curd, curs, cw, se, NE);

    gather_gemm_l1<<<(NN + 31) / 32, 256, 0, stream>>>(xb, rpd, cw, dinv, W1, bc1, Q, NN);
    gather_gemm_l2<<<(NN + 31) / 32, 256, 0, stream>>>(Q, rpd, cw, dinv, W2, bc2, P, NN);
    pool_scatter<<<CCH * 8, 256, 0, stream>>>(P, rps, se, dinv, batch, Spart, NN);
    final_k<<<NG, 256, 0, stream>>>(Spart, batch, W3, bc3, Wlin, blin, out, NN);
}

// Round 10
// 227.798 us; speedup vs baseline: 3.7811x; 3.7811x over previous
//
#include <hip/hip_runtime.h>
#include <hip/hip_bf16.h>

// GCN restructured + fused, bf16 intermediates (R6 configuration — best measured):
//   h1 = relu((Ahat x) @ W1 + b1)   -- fused gather(fp32)+GEMM, K=32 -> F=64 bf16
//   h2 = relu((Ahat h1) @ W2 + b2)  -- fused gather(bf16)+GEMM, K=64 -> F=128 bf16
//   Spart = per-graph partial segment sums of (Ahat h2)  -- fused gather(bf16)+pool
//   out = ((sum(Spart)@W3)/cnt + b3) @ Wlin + blin
// All accumulation in fp32; bf16 only for the stored/gathered h rows.

#define NN 100000
#define NE 800000
#define NG 512
#define PARTS 4

typedef unsigned int u32;

// RNE pack of two fp32 -> packed bf16x2 (lo in low half)
__device__ __forceinline__ u32 pack_bf2(float lo, float hi) {
    u32 ul = __float_as_uint(lo);
    u32 uh = __float_as_uint(hi);
    ul = (ul + 0x7fffu + ((ul >> 16) & 1u)) >> 16;
    uh = (uh + 0x7fffu + ((uh >> 16) & 1u)) & 0xffff0000u;
    return uh | ul;
}

// acc[0..7] += unpack8(v) * w
#define BF_FMA8(ACC, V, W_) do { \
    (ACC)[0] += __uint_as_float((V).x << 16) * (W_); \
    (ACC)[1] += __uint_as_float((V).x & 0xffff0000u) * (W_); \
    (ACC)[2] += __uint_as_float((V).y << 16) * (W_); \
    (ACC)[3] += __uint_as_float((V).y & 0xffff0000u) * (W_); \
    (ACC)[4] += __uint_as_float((V).z << 16) * (W_); \
    (ACC)[5] += __uint_as_float((V).z & 0xffff0000u) * (W_); \
    (ACC)[6] += __uint_as_float((V).w << 16) * (W_); \
    (ACC)[7] += __uint_as_float((V).w & 0xffff0000u) * (W_); \
} while (0)

#define FMA4(A, H, W_) do { (A).x += (H).x * (W_); (A).y += (H).y * (W_); \
                            (A).z += (H).z * (W_); (A).w += (H).w * (W_); } while (0)

// ---------------- degree ----------------
__global__ __launch_bounds__(256) void deg_count(const int* __restrict__ dst,
                                                 int* __restrict__ deg, int nE) {
    int e = blockIdx.x * 256 + threadIdx.x;
    if (e < nE) atomicAdd(&deg[dst[e]], 1);
}

// ---------------- exclusive scan of deg -> row_ptr ----------------
__global__ __launch_bounds__(256) void scanA(const int* __restrict__ deg,
                                             int* __restrict__ ex,
                                             int* __restrict__ bsum, int n) {
    __shared__ int sdata[256];
    const int t = threadIdx.x;
    const int base = blockIdx.x * 1024;
    const int idx = base + t * 4;
    int v[4];
#pragma unroll
    for (int k = 0; k < 4; ++k) v[k] = (idx + k < n) ? deg[idx + k] : 0;
    int ts = v[0] + v[1] + v[2] + v[3];
    sdata[t] = ts;
    __syncthreads();
    for (int off = 1; off < 256; off <<= 1) {
        int val = (t >= off) ? sdata[t - off] : 0;
        __syncthreads();
        sdata[t] += val;
        __syncthreads();
    }
    int run = sdata[t] - ts;
    if (t == 255) bsum[blockIdx.x] = sdata[255];
#pragma unroll
    for (int k = 0; k < 4; ++k) {
        if (idx + k < n) ex[idx + k] = run;
        run += v[k];
    }
}

__global__ __launch_bounds__(128) void scanB(int* __restrict__ bsum, int nb) {
    __shared__ int s[128];
    const int t = threadIdx.x;
    int orig = (t < nb) ? bsum[t] : 0;
    s[t] = orig;
    __syncthreads();
    for (int off = 1; off < 128; off <<= 1) {
        int val = (t >= off) ? s[t - off] : 0;
        __syncthreads();
        s[t] += val;
        __syncthreads();
    }
    if (t < nb) bsum[t] = s[t] - orig;
}

__global__ __launch_bounds__(256) void scanC(int* __restrict__ rp,
                                             const int* __restrict__ bsum,
                                             int* __restrict__ cursor,
                                             const int* __restrict__ deg,
                                             float* __restrict__ dinv,
                                             int n, int total) {
    int i = blockIdx.x * 256 + threadIdx.x;
    if (i < n) {
        int v = rp[i] + bsum[i >> 10];
        rp[i] = v;
        cursor[i] = v;
        dinv[i] = rsqrtf((float)deg[i] + 1.0f);
    }
    if (i == n) rp[n] = total;
}

// ---------------- CSR fill ----------------
__global__ __launch_bounds__(256) void fill_csr(const int* __restrict__ ei,
                                                const float* __restrict__ dinv,
                                                int* __restrict__ cursor,
                                                int2* __restrict__ cw, int nE) {
    int e = blockIdx.x * 256 + threadIdx.x;
    if (e >= nE) return;
    const int s = ei[e];
    const int d = ei[nE + e];
    const int pos = atomicAdd(&cursor[d], 1);
    const float wv = dinv[s] * dinv[d];
    cw[pos] = make_int2(s, __float_as_int(wv));
}

// ---------------- layer 1: h1 = relu((Ahat x)@W1 + b1), fp32 in, bf16 out ----
// 32 nodes/block; phase A: 8 threads/node (float4); phase B: 2 rows x 4 cols.
__global__ __launch_bounds__(256) void gather_gemm_l1(const float* __restrict__ X,
                                                      const int* __restrict__ rp,
                                                      const int2* __restrict__ cw,
                                                      const float* __restrict__ dinv,
                                                      const float* __restrict__ W,
                                                      const float* __restrict__ bias,
                                                      u32* __restrict__ out, int n) {
    constexpr int AS = 36;
    __shared__ float agg[32 * AS];
    __shared__ float Wl[32 * 64];
    float4 wr[2];
#pragma unroll
    for (int i = 0; i < 2; ++i)
        wr[i] = *reinterpret_cast<const float4*>(&W[(threadIdx.x + i * 256) * 4]);

    const int nl = threadIdx.x >> 3;
    const int j = (threadIdx.x & 7) * 4;
    const int node = blockIdx.x * 32 + nl;
    float4 a0 = make_float4(0.f, 0.f, 0.f, 0.f);
    float4 a1 = a0, a2 = a0, a3 = a0;
    if (node < n) {
        const float di = dinv[node];
        const float c = di * di;
        const float4 sv = *reinterpret_cast<const float4*>(&X[(long long)node * 32 + j]);
        FMA4(a0, sv, c);
        int e = rp[node];
        const int end = rp[node + 1];
        for (; e + 4 <= end; e += 4) {
            const int2 c0 = cw[e], c1 = cw[e + 1], c2 = cw[e + 2], c3 = cw[e + 3];
            const float4 h0 = *reinterpret_cast<const float4*>(&X[(long long)c0.x * 32 + j]);
            const float4 h1 = *reinterpret_cast<const float4*>(&X[(long long)c1.x * 32 + j]);
            const float4 h2 = *reinterpret_cast<const float4*>(&X[(long long)c2.x * 32 + j]);
            const float4 h3 = *reinterpret_cast<const float4*>(&X[(long long)c3.x * 32 + j]);
            FMA4(a0, h0, __int_as_float(c0.y));
            FMA4(a1, h1, __int_as_float(c1.y));
            FMA4(a2, h2, __int_as_float(c2.y));
            FMA4(a3, h3, __int_as_float(c3.y));
        }
        if (e + 2 <= end) {
            const int2 c0 = cw[e], c1 = cw[e + 1];
            const float4 h0 = *reinterpret_cast<const float4*>(&X[(long long)c0.x * 32 + j]);
            const float4 h1 = *reinterpret_cast<const float4*>(&X[(long long)c1.x * 32 + j]);
            FMA4(a0, h0, __int_as_float(c0.y));
            FMA4(a1, h1, __int_as_float(c1.y));
            e += 2;
        }
        if (e < end) {
            const int2 c0 = cw[e];
            const float4 h0 = *reinterpret_cast<const float4*>(&X[(long long)c0.x * 32 + j]);
            FMA4(a0, h0, __int_as_float(c0.y));
        }
        a0.x += a1.x + a2.x + a3.x; a0.y += a1.y + a2.y + a3.y;
        a0.z += a1.z + a2.z + a3.z; a0.w += a1.w + a2.w + a3.w;
    }
    *reinterpret_cast<float4*>(&agg[nl * AS + j]) = a0;
#pragma unroll
    for (int i = 0; i < 2; ++i)
        *reinterpret_cast<float4*>(&Wl[(threadIdx.x + i * 256) * 4]) = wr[i];
    __syncthreads();

    // phase B: K=32, F=64
    const int r0 = (threadIdx.x >> 4) * 2;
    const int cg = (threadIdx.x & 15) * 4;
    float4 o0 = make_float4(0.f, 0.f, 0.f, 0.f);
    float4 o1 = o0;
#pragma unroll 8
    for (int k = 0; k < 32; ++k) {
        const float4 wv = *reinterpret_cast<const float4*>(&Wl[k * 64 + cg]);
        const float x0 = agg[r0 * AS + k];
        const float x1 = agg[(r0 + 1) * AS + k];
        FMA4(o0, wv, x0);
        FMA4(o1, wv, x1);
    }
    const float4 bv = *reinterpret_cast<const float4*>(&bias[cg]);
    o0.x = fmaxf(o0.x + bv.x, 0.f); o0.y = fmaxf(o0.y + bv.y, 0.f);
    o0.z = fmaxf(o0.z + bv.z, 0.f); o0.w = fmaxf(o0.w + bv.w, 0.f);
    o1.x = fmaxf(o1.x + bv.x, 0.f); o1.y = fmaxf(o1.y + bv.y, 0.f);
    o1.z = fmaxf(o1.z + bv.z, 0.f); o1.w = fmaxf(o1.w + bv.w, 0.f);
    const int row0 = blockIdx.x * 32 + r0;
    if (row0 < n)
        *reinterpret_cast<uint2*>(&out[(long long)row0 * 32 + (cg >> 1)]) =
            make_uint2(pack_bf2(o0.x, o0.y), pack_bf2(o0.z, o0.w));
    if (row0 + 1 < n)
        *reinterpret_cast<uint2*>(&out[(long long)(row0 + 1) * 32 + (cg >> 1)]) =
            make_uint2(pack_bf2(o1.x, o1.y), pack_bf2(o1.z, o1.w));
}

// ---------------- layer 2: h2 = relu((Ahat h1)@W2 + b2), bf16 in/out ----------
__global__ __launch_bounds__(256) void gather_gemm_l2(const u32* __restrict__ X,
                                                      const int* __restrict__ rp,
                                                      const int2* __restrict__ cw,
                                                      const float* __restrict__ dinv,
                                                      const float* __restrict__ W,
                                                      const float* __restrict__ bias,
                                                      u32* __restrict__ out, int n) {
    constexpr int AS = 68;
    __shared__ float agg[32 * AS];
    __shared__ float Wl[64 * 128];
    float4 wr[8];
#pragma unroll
    for (int i = 0; i < 8; ++i)
        wr[i] = *reinterpret_cast<const float4*>(&W[(threadIdx.x + i * 256) * 4]);

    const int nl = threadIdx.x >> 3;
    const int j = threadIdx.x & 7;         // feature octet
    const int node = blockIdx.x * 32 + nl;
    float a0[8], a1[8], a2[8], a3[8];
#pragma unroll
    for (int q = 0; q < 8; ++q) { a0[q] = 0.f; a1[q] = 0.f; a2[q] = 0.f; a3[q] = 0.f; }
    if (node < n) {
        const float di = dinv[node];
        const float c = di * di;
        const uint4 sv = *reinterpret_cast<const uint4*>(&X[(long long)node * 32 + j * 4]);
        BF_FMA8(a0, sv, c);
        int e = rp[node];
        const int end = rp[node + 1];
        for (; e + 4 <= end; e += 4) {
            const int2 c0 = cw[e], c1 = cw[e + 1], c2 = cw[e + 2], c3 = cw[e + 3];
            const uint4 h0 = *reinterpret_cast<const uint4*>(&X[(long long)c0.x * 32 + j * 4]);
            const uint4 h1 = *reinterpret_cast<const uint4*>(&X[(long long)c1.x * 32 + j * 4]);
            const uint4 h2 = *reinterpret_cast<const uint4*>(&X[(long long)c2.x * 32 + j * 4]);
            const uint4 h3 = *reinterpret_cast<const uint4*>(&X[(long long)c3.x * 32 + j * 4]);
            BF_FMA8(a0, h0, __int_as_float(c0.y));
            BF_FMA8(a1, h1, __int_as_float(c1.y));
            BF_FMA8(a2, h2, __int_as_float(c2.y));
            BF_FMA8(a3, h3, __int_as_float(c3.y));
        }
        if (e + 2 <= end) {
            const int2 c0 = cw[e], c1 = cw[e + 1];
            const uint4 h0 = *reinterpret_cast<const uint4*>(&X[(long long)c0.x * 32 + j * 4]);
            const uint4 h1 = *reinterpret_cast<const uint4*>(&X[(long long)c1.x * 32 + j * 4]);
            BF_FMA8(a0, h0, __int_as_float(c0.y));
            BF_FMA8(a1, h1, __int_as_float(c1.y));
            e += 2;
        }
        if (e < end) {
            const int2 c0 = cw[e];
            const uint4 h0 = *reinterpret_cast<const uint4*>(&X[(long long)c0.x * 32 + j * 4]);
            BF_FMA8(a0, h0, __int_as_float(c0.y));
        }
#pragma unroll
        for (int q = 0; q < 8; ++q) a0[q] += a1[q] + a2[q] + a3[q];
    }
    *reinterpret_cast<float4*>(&agg[nl * AS + j * 8]) =
        make_float4(a0[0], a0[1], a0[2], a0[3]);
    *reinterpret_cast<float4*>(&agg[nl * AS + j * 8 + 4]) =
        make_float4(a0[4], a0[5], a0[6], a0[7]);
#pragma unroll
    for (int i = 0; i < 8; ++i)
        *reinterpret_cast<float4*>(&Wl[(threadIdx.x + i * 256) * 4]) = wr[i];
    __syncthreads();

    // phase B: K=64, F=128, 4 rows x 4 cols
    const int r0 = (threadIdx.x >> 5) * 4;
    const int cg = (threadIdx.x & 31) * 4;
    float4 o0 = make_float4(0.f, 0.f, 0.f, 0.f);
    float4 o1 = o0, o2 = o0, o3 = o0;
#pragma unroll 8
    for (int k = 0; k < 64; ++k) {
        const float4 wv = *reinterpret_cast<const float4*>(&Wl[k * 128 + cg]);
        const float x0 = agg[(r0 + 0) * AS + k];
        const float x1 = agg[(r0 + 1) * AS + k];
        const float x2 = agg[(r0 + 2) * AS + k];
        const float x3 = agg[(r0 + 3) * AS + k];
        FMA4(o0, wv, x0);
        FMA4(o1, wv, x1);
        FMA4(o2, wv, x2);
        FMA4(o3, wv, x3);
    }
    const float4 bv = *reinterpret_cast<const float4*>(&bias[cg]);
    const int row0 = blockIdx.x * 32 + r0;
    float4 oo[4] = {o0, o1, o2, o3};
#pragma unroll
    for (int r = 0; r < 4; ++r) {
        float4 o = oo[r];
        o.x = fmaxf(o.x + bv.x, 0.f); o.y = fmaxf(o.y + bv.y, 0.f);
        o.z = fmaxf(o.z + bv.z, 0.f); o.w = fmaxf(o.w + bv.w, 0.f);
        if (row0 + r < n)
            *reinterpret_cast<uint2*>(&out[(long long)(row0 + r) * 64 + (cg >> 1)]) =
                make_uint2(pack_bf2(o.x, o.y), pack_bf2(o.z, o.w));
    }
}

// ---------------- fused layer-3 gather(bf16) + pool partials ----------------
__device__ __forceinline__ int lower_bound_i(const int* __restrict__ a, int n, int key) {
    int lo = 0, hi = n;
    while (lo < hi) {
        int mid = (lo + hi) >> 1;
        if (a[mid] < key) lo = mid + 1; else hi = mid;
    }
    return lo;
}

__global__ __launch_bounds__(256) void gather_pool(const u32* __restrict__ H,
                                                   const int* __restrict__ rp,
                                                   const int2* __restrict__ cw,
                                                   const float* __restrict__ dinv,
                                                   const int* __restrict__ batch,
                                                   float* __restrict__ Spart, int n) {
    __shared__ float red[16 * 128];
    const int g = blockIdx.x / PARTS;
    const int part = blockIdx.x % PARTS;
    const int slot = threadIdx.x >> 4;     // 16 slots
    const int j = threadIdx.x & 15;        // feature octet 0..15
    const int start = lower_bound_i(batch, n, g);
    const int end = lower_bound_i(batch, n, g + 1);
    float a0[8], a1[8], a2[8], a3[8];
#pragma unroll
    for (int q = 0; q < 8; ++q) { a0[q] = 0.f; a1[q] = 0.f; a2[q] = 0.f; a3[q] = 0.f; }
    for (int node = start + part * 16 + slot; node < end; node += PARTS * 16) {
        const float di = dinv[node];
        const float c = di * di;
        const uint4 sv = *reinterpret_cast<const uint4*>(&H[(long long)node * 64 + j * 4]);
        BF_FMA8(a0, sv, c);
        int e = rp[node];
        const int eend = rp[node + 1];
        for (; e + 4 <= eend; e += 4) {
            const int2 c0 = cw[e], c1 = cw[e + 1], c2 = cw[e + 2], c3 = cw[e + 3];
            const uint4 h0 = *reinterpret_cast<const uint4*>(&H[(long long)c0.x * 64 + j * 4]);
            const uint4 h1 = *reinterpret_cast<const uint4*>(&H[(long long)c1.x * 64 + j * 4]);
            const uint4 h2 = *reinterpret_cast<const uint4*>(&H[(long long)c2.x * 64 + j * 4]);
            const uint4 h3 = *reinterpret_cast<const uint4*>(&H[(long long)c3.x * 64 + j * 4]);
            BF_FMA8(a0, h0, __int_as_float(c0.y));
            BF_FMA8(a1, h1, __int_as_float(c1.y));
            BF_FMA8(a2, h2, __int_as_float(c2.y));
            BF_FMA8(a3, h3, __int_as_float(c3.y));
        }
        if (e + 2 <= eend) {
            const int2 c0 = cw[e], c1 = cw[e + 1];
            const uint4 h0 = *reinterpret_cast<const uint4*>(&H[(long long)c0.x * 64 + j * 4]);
            const uint4 h1 = *reinterpret_cast<const uint4*>(&H[(long long)c1.x * 64 + j * 4]);
            BF_FMA8(a0, h0, __int_as_float(c0.y));
            BF_FMA8(a1, h1, __int_as_float(c1.y));
            e += 2;
        }
        if (e < eend) {
            const int2 c0 = cw[e];
            const uint4 h0 = *reinterpret_cast<const uint4*>(&H[(long long)c0.x * 64 + j * 4]);
            BF_FMA8(a0, h0, __int_as_float(c0.y));
        }
    }
#pragma unroll
    for (int q = 0; q < 8; ++q) a0[q] += a1[q] + a2[q] + a3[q];
    *reinterpret_cast<float4*>(&red[slot * 128 + j * 8]) =
        make_float4(a0[0], a0[1], a0[2], a0[3]);
    *reinterpret_cast<float4*>(&red[slot * 128 + j * 8 + 4]) =
        make_float4(a0[4], a0[5], a0[6], a0[7]);
    __syncthreads();
    const int t = threadIdx.x;
    if (t < 128) {
        float s = 0.f;
#pragma unroll
        for (int sl = 0; sl < 16; ++sl) s += red[sl * 128 + t];
        Spart[(long long)blockIdx.x * 128 + t] = s;
    }
}

// ---------------- final ----------------
__global__ __launch_bounds__(256) void final_k(const float* __restrict__ Spart,
                                               const int* __restrict__ batch,
                                               const float* __restrict__ W3,
                                               const float* __restrict__ b3,
                                               const float* __restrict__ Wlin,
                                               const float* __restrict__ blin,
                                               float* __restrict__ out, int n) {
    __shared__ float srow[128];
    __shared__ float prow[256];
    const int g = blockIdx.x;
    const int t = threadIdx.x;
    if (t < 128) {
        float s = 0.f;
#pragma unroll
        for (int p = 0; p < PARTS; ++p)
            s += Spart[(long long)(g * PARTS + p) * 128 + t];
        srow[t] = s;
    }
    __syncthreads();
    const int start = lower_bound_i(batch, n, g);
    const int end = lower_bound_i(batch, n, g + 1);
    const float cnt = (float)(end - start);
    const float inv = 1.0f / fmaxf(cnt, 1.0f);
    const float bscale = cnt * inv;
    float p = 0.f;
    for (int k = 0; k < 128; ++k) p += srow[k] * W3[k * 256 + t];
    prow[t] = p * inv + b3[t] * bscale;
    __syncthreads();
    if (t < 10) {
        float a = blin[t];
        for (int f = 0; f < 256; ++f) a += prow[f] * Wlin[f * 10 + t];
        out[g * 10 + t] = a;
    }
}

extern "C" void kernel_launch(void* const* d_in, const int* in_sizes, int n_in,
                              void* d_out, int out_size, void* d_ws, size_t ws_size,
                              hipStream_t stream) {
    const float* x     = (const float*)d_in[0];
    const int*   ei    = (const int*)d_in[1];
    const int*   batch = (const int*)d_in[2];
    const float* W1    = (const float*)d_in[3];
    const float* bc1   = (const float*)d_in[4];
    const float* W2    = (const float*)d_in[5];
    const float* bc2   = (const float*)d_in[6];
    const float* W3    = (const float*)d_in[7];
    const float* bc3   = (const float*)d_in[8];
    const float* Wlin  = (const float*)d_in[9];
    const float* blin  = (const float*)d_in[10];
    float* out = (float*)d_out;

    char* w = (char*)d_ws;
    int*   deg    = (int*)w;               w += 131072 * 4;
    int*   rp     = (int*)w;               w += 131072 * 4;
    int*   cursor = (int*)w;               w += 131072 * 4;
    int*   bsum   = (int*)w;               w += 256 * 4;
    float* dinv   = (float*)w;             w += 131072 * 4;
    int2*  cw     = (int2*)w;              w += (long long)NE * 8;
    u32*   Q      = (u32*)w;               w += (long long)NN * 64 * 2;   // h1 bf16
    u32*   P      = (u32*)w;               w += (long long)NN * 128 * 2;  // h2 bf16
    float* Spart  = (float*)w;             w += (long long)NG * PARTS * 128 * 4;

    const int nbScanA = (NN + 1023) / 1024;

    hipMemsetAsync(deg, 0, NN * sizeof(int), stream);
    deg_count<<<(NE + 255) / 256, 256, 0, stream>>>(ei + NE, deg, NE);
    scanA<<<nbScanA, 256, 0, stream>>>(deg, rp, bsum, NN);
    scanB<<<1, 128, 0, stream>>>(bsum, nbScanA);
    scanC<<<(NN + 256) / 256, 256, 0, stream>>>(rp, bsum, cursor, deg, dinv, NN, NE);
    fill_csr<<<(NE + 255) / 256, 256, 0, stream>>>(ei, dinv, cursor, cw, NE);

    gather_gemm_l1<<<(NN + 31) / 32, 256, 0, stream>>>(x, rp, cw, dinv, W1, bc1, Q, NN);
    gather_gemm_l2<<<(NN + 31) / 32, 256, 0, stream>>>(Q, rp, cw, dinv, W2, bc2, P, NN);
    gather_pool<<<NG * PARTS, 256, 0, stream>>>(P, rp, cw, dinv, batch, Spart, NN);
    final_k<<<NG, 256, 0, stream>>>(Spart, batch, W3, bc3, Wlin, blin, out, NN);
}